// Round 16
// baseline (5072.726 us; speedup 1.0000x reference)
//
#include <hip/hip_runtime.h>

#define B   32
#define T   64
#define D   512
#define H   512
#define H2  1024
#define G4  4096
#define V   2048
#define DEC_IN 2560

__device__ __forceinline__ float sigm(float x) { return 1.f / (1.f + expf(-x)); }

__device__ __forceinline__ unsigned fenc(float f) {
  unsigned u = __float_as_uint(f);
  return (u & 0x80000000u) ? ~u : (u | 0x80000000u);
}

__device__ __forceinline__ void st_wt(float* p, float v) {       // write-through (L3-visible on retire)
  __hip_atomic_store(p, v, __ATOMIC_RELAXED, __HIP_MEMORY_SCOPE_AGENT);
}

// ---- flat single-hop grid barrier (INV-free, R14 semantics): thread i polls slot i.
// Last arrival -> all blocks observe directly (1 L3 round-trip). No collector, no flag. ----
__device__ __forceinline__ void pbar_flat(unsigned* slots, int myid, int nmask) {
  __syncthreads();   // drains vmcnt -> write-through stores L3-visible before arrival
  if (threadIdx.x == 0)
    __hip_atomic_store(slots + myid, 1u, __ATOMIC_RELAXED, __HIP_MEMORY_SCOPE_AGENT);
  {
    unsigned* s = slots + (threadIdx.x & nmask);
    while (!__hip_atomic_load(s, __ATOMIC_RELAXED, __HIP_MEMORY_SCOPE_AGENT))
      __builtin_amdgcn_s_sleep(1);
  }
  __syncthreads();
}

// ---------------- fp32 GEMM: 128x128 tile, 8x8 micro-tile, BK=8, dbuf global loads ------
__global__ __launch_bounds__(256) void gemm_nt(
    const float* __restrict__ A, int lda,
    const float* __restrict__ W, int ldw,
    float* __restrict__ C, int ldc,
    const float* __restrict__ bias0, const float* __restrict__ bias1,
    int K)
{
  __shared__ float As[8][132];
  __shared__ float Bs[8][132];
  const int tid = threadIdx.x;
  const int nb = blockIdx.x * 128;
  const int mb = blockIdx.y * 128;
  const int tx = tid & 15;
  const int ty = tid >> 4;
  float acc[8][8] = {};

  const int am = tid >> 1, ak = (tid & 1) * 4;
  const float* aptr = A + (size_t)(mb + am) * lda + ak;
  const float* bptr = W + (size_t)(nb + am) * ldw + ak;

  float4 av = *(const float4*)(aptr);
  float4 bv = *(const float4*)(bptr);
  for (int k0 = 0; k0 < K; k0 += 8) {
    As[ak+0][am] = av.x; As[ak+1][am] = av.y; As[ak+2][am] = av.z; As[ak+3][am] = av.w;
    Bs[ak+0][am] = bv.x; Bs[ak+1][am] = bv.y; Bs[ak+2][am] = bv.z; Bs[ak+3][am] = bv.w;
    __syncthreads();
    float4 avn = av, bvn = bv;
    if (k0 + 8 < K) {      // issue next tile's loads early; latency hides under FMAs
      avn = *(const float4*)(aptr + k0 + 8);
      bvn = *(const float4*)(bptr + k0 + 8);
    }
    #pragma unroll
    for (int k = 0; k < 8; ++k) {
      float4 a0 = *(const float4*)&As[k][ty*8];
      float4 a1 = *(const float4*)&As[k][ty*8+4];
      float4 b0 = *(const float4*)&Bs[k][tx*8];
      float4 b1 = *(const float4*)&Bs[k][tx*8+4];
      float avv[8] = {a0.x,a0.y,a0.z,a0.w,a1.x,a1.y,a1.z,a1.w};
      float bvv[8] = {b0.x,b0.y,b0.z,b0.w,b1.x,b1.y,b1.z,b1.w};
      #pragma unroll
      for (int i = 0; i < 8; ++i)
        #pragma unroll
        for (int j = 0; j < 8; ++j)
          acc[i][j] += avv[i]*bvv[j];
    }
    __syncthreads();
    av = avn; bv = bvn;
  }
  float b8[8];
  #pragma unroll
  for (int j = 0; j < 8; ++j) {
    float bvv = 0.f;
    if (bias0) bvv += bias0[nb + tx*8 + j];
    if (bias1) bvv += bias1[nb + tx*8 + j];
    b8[j] = bvv;
  }
  #pragma unroll
  for (int i = 0; i < 8; ++i) {
    float4 o0, o1;
    o0.x = acc[i][0]+b8[0]; o0.y = acc[i][1]+b8[1]; o0.z = acc[i][2]+b8[2]; o0.w = acc[i][3]+b8[3];
    o1.x = acc[i][4]+b8[4]; o1.y = acc[i][5]+b8[5]; o1.z = acc[i][6]+b8[6]; o1.w = acc[i][7]+b8[7];
    size_t idx = (size_t)(mb + ty*8 + i) * ldc + nb + tx*8;
    *(float4*)&C[idx]     = o0;
    *(float4*)&C[idx + 4] = o1;
  }
}

// ---------------- distributed attention: block (ab, aslice) -> ctx slice ----------------
__device__ void attend_slice(int ab, int aslice, const float* __restrict__ hvec,
                             float* __restrict__ ctxdst,
                             const float* __restrict__ outbuf, const float* __restrict__ projo,
                             const int* __restrict__ mask, float* scratch, int tid)
{
  float* scp = scratch;        // 256
  float* scv = scratch + 256;  // 64
  float* p2  = scratch + 320;  // 128
  const int tq = tid >> 2, dq = tid & 3;
  const float4* hv = (const float4*)(hvec + dq*256);
  const float4* pv = (const float4*)(projo + (size_t)(ab*T + tq)*H2 + dq*256);
  float p = 0.f;
  #pragma unroll 8
  for (int k4 = 0; k4 < 64; ++k4) {
    float4 a = hv[k4], q = pv[k4];
    p += a.x*q.x + a.y*q.y + a.z*q.z + a.w*q.w;
  }
  scp[tid] = p;
  __syncthreads();
  if (tid < 64) {
    float v = scp[tid*4] + scp[tid*4+1] + scp[tid*4+2] + scp[tid*4+3];
    float mx = v;
    #pragma unroll
    for (int d = 32; d; d >>= 1) mx = fmaxf(mx, __shfl_xor(mx, d, 64));
    float e = expf(v - mx);
    float sm = e;
    #pragma unroll
    for (int d = 32; d; d >>= 1) sm += __shfl_xor(sm, d, 64);
    scv[tid] = e * (1.f / sm) * (float)mask[ab*T + tid];
  }
  __syncthreads();
  {
    const int dl = tid & 127, th = tid >> 7;
    const int dg = aslice*128 + dl;
    float acc = 0.f;
    #pragma unroll 8
    for (int q = 0; q < 32; ++q) {
      int tt = th*32 + q;
      acc += scv[tt] * outbuf[(size_t)(ab*T + tt)*H2 + dg];
    }
    if (th == 1) p2[dl] = acc;
    __syncthreads();
    if (th == 0) st_wt(&ctxdst[dg*32 + ab], acc + p2[dl]);
  }
}

// ---------------- persistent encoder: rotating h buffers, flat INV-free barriers --------
__global__ __launch_bounds__(256, 1) void encoder_persistent(
    const float* __restrict__ xg_f, const float* __restrict__ xg_b,
    const float* __restrict__ Whh_f, const float* __restrict__ Whh_b,
    const int* __restrict__ mask,
    float* __restrict__ hebufs,      // [2][64][512][32] rotating h
    const float* __restrict__ zeroh, // zeros (h(-1))
    float* __restrict__ outbuf,
    unsigned* __restrict__ eslots)
{
  __shared__ float S_lds[9216];   // wave-private: wv*2304 + buf*1152, rows stride 36
  __shared__ float pacc[2048];
  __shared__ float g_lds[512];
  const int blk = blockIdx.x, tid = threadIdx.x;
  const int lane = tid & 63, wv = tid >> 6;
  const int dir = blk >> 7, nd = blk & 127;
  const int hibase = nd * 4;
  const int jj = tid & 7, kk = tid >> 3;
  const int kkl = lane >> 3;
  const float* xg  = dir ? xg_b : xg_f;
  const float* Whh = dir ? Whh_b : Whh_f;
  float* hebase = hebufs + (size_t)dir * 1048576;
  float* Sw = S_lds + wv*2304;

  float wge[2][16];
  #pragma unroll
  for (int p = 0; p < 2; ++p) {
    int jl = jj*2 + p;
    int j = (jl>>2)*512 + hibase + (jl&3);
    #pragma unroll
    for (int sc = 0; sc < 4; ++sc)
      #pragma unroll
      for (int i = 0; i < 4; ++i)
        wge[p][sc*4+i] = Whh[(size_t)j*512 + sc*128 + i*32 + kk];
  }
  float c_reg = 0.f;
  const int lr = lane >> 1, halfc = (lane & 1) * 16;
  const int grow = (lr >> 3)*32 + 8*wv + (lr & 7);

  for (int tt = 0; tt < 64; ++tt) {
    const int t = dir ? (63 - tt) : tt;
    const float* hc = tt ? (hebase + (size_t)(tt-1)*16384) : zeroh;
    float* hn = hebase + (size_t)tt*16384;

    float a0[32], a1[32];
    #pragma unroll
    for (int q = 0; q < 32; ++q) { a0[q] = 0.f; a1[q] = 0.f; }

    float4 r0, r1, r2, r3;
    {
      const float4* p = (const float4*)(hc + grow*32 + halfc);
      r0 = p[0]; r1 = p[1]; r2 = p[2]; r3 = p[3];
      float* d = Sw + lr*36 + halfc;
      *(float4*)d = r0; *(float4*)(d+4) = r1; *(float4*)(d+8) = r2; *(float4*)(d+12) = r3;
    }
    #pragma unroll
    for (int sc = 0; sc < 4; ++sc) {
      if (sc < 3) {
        const float4* p = (const float4*)(hc + ((sc+1)*128 + grow)*32 + halfc);
        r0 = p[0]; r1 = p[1]; r2 = p[2]; r3 = p[3];
      }
      const float* Sb = Sw + (sc & 1)*1152;
      #pragma unroll
      for (int i = 0; i < 4; ++i) {
        const float* sp = Sb + (i*8 + kkl)*36;
        float w0 = wge[0][sc*4+i], w1 = wge[1][sc*4+i];
        #pragma unroll
        for (int q = 0; q < 8; ++q) {
          float4 s4 = *(const float4*)(sp + q*4);
          a0[q*4+0] += w0*s4.x; a0[q*4+1] += w0*s4.y; a0[q*4+2] += w0*s4.z; a0[q*4+3] += w0*s4.w;
          a1[q*4+0] += w1*s4.x; a1[q*4+1] += w1*s4.y; a1[q*4+2] += w1*s4.z; a1[q*4+3] += w1*s4.w;
        }
      }
      if (sc < 3) {
        float* d = Sw + ((sc+1) & 1)*1152 + lr*36 + halfc;
        *(float4*)d = r0; *(float4*)(d+4) = r1; *(float4*)(d+8) = r2; *(float4*)(d+12) = r3;
      }
    }
    #pragma unroll
    for (int dd = 8; dd <= 32; dd <<= 1) {
      #pragma unroll
      for (int q = 0; q < 32; ++q) {
        a0[q] += __shfl_down(a0[q], dd, 64);
        a1[q] += __shfl_down(a1[q], dd, 64);
      }
    }
    if (lane < 8) {
      float* pw = &pacc[wv*512 + lane*64];
      #pragma unroll
      for (int q = 0; q < 32; ++q) { pw[q] = a0[q]; pw[32+q] = a1[q]; }
    }
    __syncthreads();
    #pragma unroll
    for (int r = 0; r < 2; ++r) {
      int o = tid + r*256;
      int jl = o >> 5, b = o & 31;
      int off = (jl>>1)*64 + (jl&1)*32 + b;
      float v = pacc[off] + pacc[512+off] + pacc[1024+off] + pacc[1536+off];
      v += xg[(size_t)(b*T + t)*2048 + (jl>>2)*512 + hibase + (jl&3)];
      g_lds[jl*32 + b] = v;
    }
    __syncthreads();
    if (tid < 128) {
      int hil = tid >> 5, b = tid & 31;
      float gi = g_lds[(0*4+hil)*32 + b];
      float gf = g_lds[(1*4+hil)*32 + b];
      float gg = g_lds[(2*4+hil)*32 + b];
      float go = g_lds[(3*4+hil)*32 + b];
      c_reg = sigm(gf)*c_reg + sigm(gi)*tanhf(gg);
      float h = sigm(go)*tanhf(c_reg);
      int hi = hibase + hil;
      st_wt(&hn[hi*32 + b], h);
      st_wt(&outbuf[(size_t)(b*T + t)*H2 + dir*512 + hi], h * (float)mask[b*T + t]);
    }
    pbar_flat(eslots + (dir*64 + tt)*128, nd, 127);
  }
}

// ---- decoder macros: wave-private staging (NO __syncthreads in K-loops) ----
#define GROW1(lr) (8*wv + ((lr) < 8 ? (lr) : 24 + (lr)))
#define GROW2(lr) (16*wv + (lr))
#define SLDG(qq, s) { int krr = (s)*64 + GROW1(lrow); \
  const float* bs = (krr < 1024) ? (hTc + krr*32) : (ctxc + (krr-1024)*32); \
  qq##a = *(const float4*)(bs + scol2); qq##b = *(const float4*)(bs + scol2 + 4); }
#define SLDS(qq, s) { int krr = (s)*64 + GROW2(lrow); \
  const float* bs = (krr < 1024) ? (hTn + krr*32) : (ctxc + (krr-1024)*32); \
  qq##a = *(const float4*)(bs + scol2); qq##b = *(const float4*)(bs + scol2 + 4); }
#define STW(qq, BUF) { float* d = Sw + (BUF)*576 + lrow*36 + scol2; \
  *(float4*)d = qq##a; *(float4*)(d+4) = qq##b; }
#define COMPG(sl, BUF) { const float* Sb = Sw + (BUF)*576; \
  _Pragma("unroll") for (int i = 0; i < 2; ++i) { \
    float w0 = Wg[jl0*2052 + (sl)*64 + i*32 + kkg]; \
    float w1 = Wg[jl1*2052 + (sl)*64 + i*32 + kkg]; \
    const float* sp = Sb + (i*8 + kkl)*36; \
    _Pragma("unroll") for (int q = 0; q < 8; ++q) { \
      float4 s4 = *(const float4*)(sp + q*4); \
      a0[q*4+0] += w0*s4.x; a0[q*4+1] += w0*s4.y; a0[q*4+2] += w0*s4.z; a0[q*4+3] += w0*s4.w; \
      a1[q*4+0] += w1*s4.x; a1[q*4+1] += w1*s4.y; a1[q*4+2] += w1*s4.z; a1[q*4+3] += w1*s4.w; } } }
#define COMPS(sl, BUF) { const float* sp = Sw + (BUF)*576 + lrow*36; \
  float w0 = ws0[sl], w1 = ws1[sl]; \
  _Pragma("unroll") for (int q = 0; q < 8; ++q) { \
    float4 s4 = *(const float4*)(sp + q*4); \
    a0[q*4+0] += w0*s4.x; a0[q*4+1] += w0*s4.y; a0[q*4+2] += w0*s4.z; a0[q*4+3] += w0*s4.w; \
    a1[q*4+0] += w1*s4.x; a1[q*4+1] += w1*s4.y; a1[q*4+2] += w1*s4.z; a1[q*4+3] += w1*s4.w; } }

// ---------------- persistent decoder: rotating state, flat INV-free barriers ------------
// Dynamic LDS (floats): Wg 16x2052=32832 | S2 4x2x576=4608 | pacc 2048 | g_lds 512 = 160000 B
__global__ __launch_bounds__(256, 1) void decoder_persistent(
    const float* __restrict__ basep, const float* __restrict__ tagp,
    const float* __restrict__ dWhh,  const float* __restrict__ dWih,
    const float* __restrict__ Wout,  const float* __restrict__ bout,
    const float* __restrict__ projo, const float* __restrict__ outbuf,
    const int* __restrict__ mask,
    float* __restrict__ hbufs,       // [64][1024][32] rotating h (transposed)
    float* __restrict__ cbufs,       // [65][1024][32] rotating ctx (transposed)
    float* __restrict__ rbufs,       // [64][32][1024] rotating h (row-major)
    const float* __restrict__ zeroh, // [1024][32] zeros (h(-1))
    unsigned long long* __restrict__ argslot,
    unsigned* __restrict__ dslots,
    float* __restrict__ out)
{
  extern __shared__ float dyn[];
  float* Wg    = dyn;           // 32832
  float* S2    = dyn + 32832;   // 4608 (wave-private: wv*1152 + buf*576)
  float* pacc  = dyn + 37440;   // 2048
  float* g_lds = dyn + 39488;   // 512

  const int blk = blockIdx.x, tid = threadIdx.x;
  const int lane = tid & 63, wv = tid >> 6;
  const int hibase = blk * 4;
  const int jj = lane & 7, kkl = lane >> 3;
  const int kkg = 8*wv + kkl;
  const int jl0 = jj*2, jl1 = jj*2 + 1;
  const int vv = tid & 3, kq = tid >> 2;
  const int vbase = blk * 8;
  const int lrow = lane >> 2, scol2 = (lane & 3) * 8;
  const int ab = blk & 31, aslice = blk >> 5;   // XCD-localized attend mapping
  float* Sw = S2 + wv*1152;

  // ---- preload gates weights into LDS (once) ----
  for (int jl = 0; jl < 16; ++jl) {
    int j = (jl>>2)*1024 + hibase + (jl&3);
    #pragma unroll
    for (int r = 0; r < 2; ++r) {
      int c = tid*4 + r*1024;
      float4 w;
      if (c < 1024) w = *(const float4*)(dWhh + (size_t)j*1024 + c);
      else          w = *(const float4*)(dWih + (size_t)j*2560 + 512 + (c - 1024));
      *(float4*)&Wg[jl*2052 + c] = w;
    }
  }
  // ---- scores weights in registers (64 floats/thread) ----
  float ws0[32], ws1[32];
  {
    int v0 = vbase + vv*2;
    #pragma unroll
    for (int s2 = 0; s2 < 32; ++s2) {
      ws0[s2] = Wout[(size_t)(v0+0)*2048 + s2*64 + kq];
      ws1[s2] = Wout[(size_t)(v0+1)*2048 + s2*64 + kq];
    }
  }

  float c_reg = 0.f;
  int bslot = 0;

  // ---- prologue: ctx(0) = attend(last_output) -> cbufs[0] ----
  {
    int len = -1;
    for (int i = 0; i < T; ++i) len += mask[ab*T + i];
    attend_slice(ab, aslice, outbuf + (size_t)(ab*T + len)*H2, cbufs,
                 outbuf, projo, mask, pacc, tid);
  }
  pbar_flat(dslots + (bslot)*256, blk, 255); bslot++;

  for (int t = 0; t < T; ++t) {
    const float* hTc  = (t == 0) ? zeroh : (hbufs + (size_t)(t-1)*32768);
    float*       hTn  = hbufs + (size_t)t*32768;
    const float* ctxc = cbufs + (size_t)t*32768;
    float*       ctxn = cbufs + (size_t)(t+1)*32768;
    float*       hrw  = rbufs + (size_t)t*32768;

    const int b_own = tid & 31;
    const int jlA = tid >> 5, jlB = jlA + 8;
    const int jA = (jlA>>2)*1024 + hibase + (jlA&3);
    const int jB = (jlB>>2)*1024 + hibase + (jlB&3);
    float extA = basep[(size_t)(b_own*T + t)*G4 + jA];
    float extB = basep[(size_t)(b_own*T + t)*G4 + jB];
    if (t > 0) {
      unsigned long long sl64 = __hip_atomic_load(&argslot[((t+2)%3)*32 + b_own],
                                                  __ATOMIC_RELAXED, __HIP_MEMORY_SCOPE_AGENT);
      unsigned tg = ~(unsigned)sl64;
      extA += tagp[(size_t)tg*G4 + jA];
      extB += tagp[(size_t)tg*G4 + jB];
    }

    // ===== phase 1: gates (K=2048: h | ctx), wave-private staging, no K-loop syncs =====
    float a0[32], a1[32];
    #pragma unroll
    for (int q = 0; q < 32; ++q) { a0[q] = 0.f; a1[q] = 0.f; }
    {
      float4 q0a,q0b,q1a,q1b,q2a,q2b,q3a,q3b;
      SLDG(q0, 0) SLDG(q1, 1) SLDG(q2, 2) SLDG(q3, 3)
      STW(q0, 0)
      for (int g = 0; g < 8; ++g) {
        const int sl = g*4;
        if (sl+4 < 32) SLDG(q0, sl+4)
        COMPG(sl, 0)
        STW(q1, 1)
        if (sl+5 < 32) SLDG(q1, sl+5)
        COMPG(sl+1, 1)
        STW(q2, 0)
        if (sl+6 < 32) SLDG(q2, sl+6)
        COMPG(sl+2, 0)
        STW(q3, 1)
        if (sl+7 < 32) SLDG(q3, sl+7)
        COMPG(sl+3, 1)
        if (sl+4 < 32) STW(q0, 0)
      }
    }
    #pragma unroll
    for (int dd = 8; dd <= 32; dd <<= 1) {
      #pragma unroll
      for (int q = 0; q < 32; ++q) {
        a0[q] += __shfl_down(a0[q], dd, 64);
        a1[q] += __shfl_down(a1[q], dd, 64);
      }
    }
    if (lane < 8) {
      float* pw = &pacc[wv*512 + lane*64];
      #pragma unroll
      for (int q = 0; q < 32; ++q) { pw[q] = a0[q]; pw[32+q] = a1[q]; }
    }
    __syncthreads();
    #pragma unroll
    for (int r = 0; r < 2; ++r) {
      int o = tid + r*256;
      int jl = o >> 5, b = o & 31;
      int off = (jl>>1)*64 + (jl&1)*32 + b;
      float vsum = pacc[off] + pacc[512+off] + pacc[1024+off] + pacc[1536+off];
      vsum += (r == 0) ? extA : extB;
      g_lds[jl*32 + b] = vsum;
    }
    __syncthreads();
    if (tid < 128) {
      int hil = tid >> 5, b = tid & 31;
      float gi = g_lds[(0*4+hil)*32 + b];
      float gf = g_lds[(1*4+hil)*32 + b];
      float gg = g_lds[(2*4+hil)*32 + b];
      float go = g_lds[(3*4+hil)*32 + b];
      c_reg = sigm(gf)*c_reg + sigm(gi)*tanhf(gg);
      float h = sigm(go)*tanhf(c_reg);
      int hi = hibase + hil;
      st_wt(&hTn[hi*32 + b], h);
      st_wt(&hrw[b*1024 + hi], h);
    }
    pbar_flat(dslots + (bslot)*256, blk, 255); bslot++;

    // ===== phase 2: scores (K=2048: h_new | ctx_old), wave-private staging =====
    #pragma unroll
    for (int q = 0; q < 32; ++q) { a0[q] = 0.f; a1[q] = 0.f; }
    {
      float4 q0a,q0b,q1a,q1b,q2a,q2b,q3a,q3b;
      SLDS(q0, 0) SLDS(q1, 1) SLDS(q2, 2) SLDS(q3, 3)
      STW(q0, 0)
      #pragma unroll
      for (int g = 0; g < 8; ++g) {
        const int sl = g*4;
        if (sl+4 < 32) SLDS(q0, sl+4)
        COMPS(sl, 0)
        STW(q1, 1)
        if (sl+5 < 32) SLDS(q1, sl+5)
        COMPS(sl+1, 1)
        STW(q2, 0)
        if (sl+6 < 32) SLDS(q2, sl+6)
        COMPS(sl+2, 0)
        STW(q3, 1)
        if (sl+7 < 32) SLDS(q3, sl+7)
        COMPS(sl+3, 1)
        if (sl+4 < 32) STW(q0, 0)
      }
    }
    #pragma unroll
    for (int dd = 4; dd <= 32; dd <<= 1) {
      #pragma unroll
      for (int q = 0; q < 32; ++q) {
        a0[q] += __shfl_down(a0[q], dd, 64);
        a1[q] += __shfl_down(a1[q], dd, 64);
      }
    }
    if (lane < 4) {
      float* pw = &pacc[wv*256 + lane*64];
      #pragma unroll
      for (int q = 0; q < 32; ++q) { pw[q] = a0[q]; pw[32+q] = a1[q]; }
    }
    __syncthreads();
    {
      int vl = tid & 7, b = tid >> 3;
      int off = (vl>>1)*64 + (vl&1)*32 + b;
      float s = pacc[off] + pacc[256+off] + pacc[512+off] + pacc[768+off];
      s += bout[vbase + vl];
      st_wt(&out[(size_t)(b*T + t)*V + vbase + vl], s);
      g_lds[vl*32 + b] = s;
    }
    __syncthreads();
    if (tid < 32) {
      int b = tid;
      float best = g_lds[b]; int bi = 0;
      #pragma unroll
      for (int vl = 1; vl < 8; ++vl) {
        float s = g_lds[vl*32 + b];
        if (s > best) { best = s; bi = vl; }
      }
      unsigned long long e = ((unsigned long long)fenc(best) << 32)
                           | (unsigned long long)(unsigned)(~(unsigned)(vbase + bi));
      atomicMax(&argslot[(t%3)*32 + b], e);
    } else if (blk == 0 && tid >= 32 && tid < 64) {
      __hip_atomic_store(&argslot[((t+1)%3)*32 + (tid - 32)], 0ull,
                         __ATOMIC_RELAXED, __HIP_MEMORY_SCOPE_AGENT);
    }
    if (t < 63) {
      __syncthreads();
      attend_slice(ab, aslice, hrw + ab*1024, ctxn, outbuf, projo, mask, pacc, tid);
    }
    pbar_flat(dslots + (bslot)*256, blk, 255); bslot++;
  }
}

// ---------------- host launch ----------------
extern "C" void kernel_launch(void* const* d_in, const int* in_sizes, int n_in,
                              void* d_out, int out_size, void* d_ws, size_t ws_size,
                              hipStream_t stream)
{
  (void)in_sizes; (void)n_in; (void)out_size; (void)ws_size;
  const float* emb    = (const float*)d_in[0];
  const int*   mask   = (const int*)d_in[1];
  const float* Wih_f  = (const float*)d_in[2];
  const float* Whh_f  = (const float*)d_in[3];
  const float* bih_f  = (const float*)d_in[4];
  const float* bhh_f  = (const float*)d_in[5];
  const float* Wih_b  = (const float*)d_in[6];
  const float* Whh_b  = (const float*)d_in[7];
  const float* bih_b  = (const float*)d_in[8];
  const float* bhh_b  = (const float*)d_in[9];
  const float* attnW  = (const float*)d_in[10];
  const float* tagemb = (const float*)d_in[12];
  const float* dWih   = (const float*)d_in[13];
  const float* dWhh   = (const float*)d_in[14];
  const float* dbih   = (const float*)d_in[15];
  const float* dbhh   = (const float*)d_in[16];
  const float* Wout   = (const float*)d_in[17];
  const float* bout   = (const float*)d_in[18];
  float* out = (float*)d_out;

  float* ws = (float*)d_ws;
  // Region reuse across the pipeline (stream order guarantees no overlap in time):
  //  - xg region: GEMMs 1-2 write, encoder reads; then decoder recycles it as
  //    rotating state (hbufs/cbufs/rbufs).
  //  - basep region: encoder recycles it as rotating h (hebufs); then the basep
  //    GEMM overwrites it before the decoder reads basep.
  float* xg_f   = ws + 0;          // 4194304
  float* xg_b   = ws + 4194304;    // 4194304
  float* hbufs  = ws + 0;          // 64*32768 = 2097152   (decoder h rotation)
  float* cbufs  = ws + 2097152;    // 65*32768 = 2129920   (decoder ctx rotation)
  float* rbufs  = ws + 4227072;    // 64*32768 = 2097152   (decoder hrow rotation)
  float* outbuf = ws + 8388608;    // 2097152
  float* projo  = ws + 10485760;   // 2097152
  float* basep  = ws + 12582912;   // 8388608
  float* hebufs = ws + 12582912;   // 2*64*16384 = 2097152 (encoder h rotation, pre-basep)
  float* tagp   = ws + 20971520;   // 8388608
  // --- zeroed state block ---
  float* zeroh  = ws + 29360128;   // 32768 zeros (h(-1) for both kernels)
  unsigned long long* argslot = (unsigned long long*)(ws + 29589504);  // 96 u64 (192 fl)
  unsigned* dslots = (unsigned*)(ws + 29589696);   // 129*256 = 33024 u32
  unsigned* eslots = (unsigned*)(ws + 29622720);   // 128*128 = 16384 u32
  // end: 29639104 floats

  // allow 160000 B dynamic LDS for the decoder
  (void)hipFuncSetAttribute((const void*)decoder_persistent,
                            hipFuncAttributeMaxDynamicSharedMemorySize, 160000);

  // zero all persistent-kernel state every call (graph-replay deterministic)
  hipMemsetAsync((void*)(ws + 29360128), 0, (size_t)(29639104 - 29360128) * sizeof(float), stream);

  // xg = emb @ Wih^T + bih + bhh   (M=2048, N=2048, K=512)
  gemm_nt<<<dim3(16, 16), 256, 0, stream>>>(emb, 512, Wih_f, 512, xg_f, 2048, bih_f, bhh_f, 512);
  gemm_nt<<<dim3(16, 16), 256, 0, stream>>>(emb, 512, Wih_b, 512, xg_b, 2048, bih_b, bhh_b, 512);
  // tagp = tag_embed @ dec_Wih[:, :512]^T   (M=2048, N=4096, K=512)
  gemm_nt<<<dim3(32, 16), 256, 0, stream>>>(tagemb, 512, dWih, DEC_IN, tagp, G4, nullptr, nullptr, 512);
  // encoder scan (rotating h, flat INV-free barriers)
  encoder_persistent<<<256, 256, 0, stream>>>(xg_f, xg_b, Whh_f, Whh_b, mask,
                                              hebufs, zeroh, outbuf, eslots);
  // projo[bt,d] = sum_e attn_W[d,e]*output[bt,e]   (M=2048, N=1024, K=1024)
  gemm_nt<<<dim3(8, 16), 256, 0, stream>>>(outbuf, H2, attnW, H2, projo, H2, nullptr, nullptr, H2);
  // basep = aligned @ dec_Wih[:,1536:]^T + dbih + dbhh   (M=2048, N=4096, K=1024)
  gemm_nt<<<dim3(32, 16), 256, 0, stream>>>(outbuf, H2, dWih + 1536, DEC_IN, basep, G4, dbih, dbhh, H2);
  // persistent decoder (flat INV-free barriers)
  decoder_persistent<<<256, 256, 160000, stream>>>(basep, tagp, dWhh, dWih, Wout, bout,
                                                   projo, outbuf, mask, hbufs, cbufs, rbufs, zeroh,
                                                   argslot, dslots, out);
}

// Round 17
// 4412.796 us; speedup vs baseline: 1.1495x; 1.1495x over previous
//
#include <hip/hip_runtime.h>

#define B   32
#define T   64
#define D   512
#define H   512
#define H2  1024
#define G4  4096
#define V   2048
#define DEC_IN 2560

__device__ __forceinline__ float sigm(float x) { return 1.f / (1.f + expf(-x)); }

__device__ __forceinline__ unsigned fenc(float f) {
  unsigned u = __float_as_uint(f);
  return (u & 0x80000000u) ? ~u : (u | 0x80000000u);
}

__device__ __forceinline__ void st_wt(float* p, float v) {       // write-through (L3-visible on retire)
  __hip_atomic_store(p, v, __ATOMIC_RELAXED, __HIP_MEMORY_SCOPE_AGENT);
}

// ---- INV-free store-based grid barrier (R15-proven best): collector + 16 replicated
// flags. All cross-step state uses step-unique addresses + write-through stores -> no
// acquire needed; read-only data stays L2-resident across the whole persistent kernel.
// Poll fan-in is minimal: 256 slots polled by ONE block; flags polled 1 thread/block
// across 16 replicated lines (R16's flat variant regressed from poll contention). ----
__device__ __forceinline__ void pbar_na(unsigned* slots, unsigned* flags, int myid, int nblk) {
  __syncthreads();   // drains vmcnt -> write-through stores L3-visible before arrival
  if (threadIdx.x == 0)
    __hip_atomic_store(slots + myid, 1u, __ATOMIC_RELAXED, __HIP_MEMORY_SCOPE_AGENT);
  if (myid == 0) {
    for (int s = threadIdx.x; s < nblk; s += 256) {
      while (!__hip_atomic_load(slots + s, __ATOMIC_RELAXED, __HIP_MEMORY_SCOPE_AGENT))
        __builtin_amdgcn_s_sleep(1);
    }
    __syncthreads();
    if (threadIdx.x < 16)
      __hip_atomic_store(flags + threadIdx.x*16, 1u, __ATOMIC_RELAXED, __HIP_MEMORY_SCOPE_AGENT);
  }
  if (threadIdx.x == 0) {
    unsigned* f = flags + (myid & 15)*16;
    while (!__hip_atomic_load(f, __ATOMIC_RELAXED, __HIP_MEMORY_SCOPE_AGENT))
      __builtin_amdgcn_s_sleep(1);
  }
  __syncthreads();
}

// ---------------- fp32 GEMM: 128x128 tile, 8x8 micro-tile, BK=8, dbuf global loads ------
__global__ __launch_bounds__(256) void gemm_nt(
    const float* __restrict__ A, int lda,
    const float* __restrict__ W, int ldw,
    float* __restrict__ C, int ldc,
    const float* __restrict__ bias0, const float* __restrict__ bias1,
    int K)
{
  __shared__ float As[8][132];
  __shared__ float Bs[8][132];
  const int tid = threadIdx.x;
  const int nb = blockIdx.x * 128;
  const int mb = blockIdx.y * 128;
  const int tx = tid & 15;
  const int ty = tid >> 4;
  float acc[8][8] = {};

  const int am = tid >> 1, ak = (tid & 1) * 4;
  const float* aptr = A + (size_t)(mb + am) * lda + ak;
  const float* bptr = W + (size_t)(nb + am) * ldw + ak;

  float4 av = *(const float4*)(aptr);
  float4 bv = *(const float4*)(bptr);
  for (int k0 = 0; k0 < K; k0 += 8) {
    As[ak+0][am] = av.x; As[ak+1][am] = av.y; As[ak+2][am] = av.z; As[ak+3][am] = av.w;
    Bs[ak+0][am] = bv.x; Bs[ak+1][am] = bv.y; Bs[ak+2][am] = bv.z; Bs[ak+3][am] = bv.w;
    __syncthreads();
    float4 avn = av, bvn = bv;
    if (k0 + 8 < K) {      // issue next tile's loads early; latency hides under FMAs
      avn = *(const float4*)(aptr + k0 + 8);
      bvn = *(const float4*)(bptr + k0 + 8);
    }
    #pragma unroll
    for (int k = 0; k < 8; ++k) {
      float4 a0 = *(const float4*)&As[k][ty*8];
      float4 a1 = *(const float4*)&As[k][ty*8+4];
      float4 b0 = *(const float4*)&Bs[k][tx*8];
      float4 b1 = *(const float4*)&Bs[k][tx*8+4];
      float avv[8] = {a0.x,a0.y,a0.z,a0.w,a1.x,a1.y,a1.z,a1.w};
      float bvv[8] = {b0.x,b0.y,b0.z,b0.w,b1.x,b1.y,b1.z,b1.w};
      #pragma unroll
      for (int i = 0; i < 8; ++i)
        #pragma unroll
        for (int j = 0; j < 8; ++j)
          acc[i][j] += avv[i]*bvv[j];
    }
    __syncthreads();
    av = avn; bv = bvn;
  }
  float b8[8];
  #pragma unroll
  for (int j = 0; j < 8; ++j) {
    float bvv = 0.f;
    if (bias0) bvv += bias0[nb + tx*8 + j];
    if (bias1) bvv += bias1[nb + tx*8 + j];
    b8[j] = bvv;
  }
  #pragma unroll
  for (int i = 0; i < 8; ++i) {
    float4 o0, o1;
    o0.x = acc[i][0]+b8[0]; o0.y = acc[i][1]+b8[1]; o0.z = acc[i][2]+b8[2]; o0.w = acc[i][3]+b8[3];
    o1.x = acc[i][4]+b8[4]; o1.y = acc[i][5]+b8[5]; o1.z = acc[i][6]+b8[6]; o1.w = acc[i][7]+b8[7];
    size_t idx = (size_t)(mb + ty*8 + i) * ldc + nb + tx*8;
    *(float4*)&C[idx]     = o0;
    *(float4*)&C[idx + 4] = o1;
  }
}

// ---------------- distributed attention: block (ab, aslice) -> ctx slice ----------------
__device__ void attend_slice(int ab, int aslice, const float* __restrict__ hvec,
                             float* __restrict__ ctxdst,
                             const float* __restrict__ outbuf, const float* __restrict__ projo,
                             const int* __restrict__ mask, float* scratch, int tid)
{
  float* scp = scratch;        // 256
  float* scv = scratch + 256;  // 64
  float* p2  = scratch + 320;  // 128
  const int tq = tid >> 2, dq = tid & 3;
  const float4* hv = (const float4*)(hvec + dq*256);
  const float4* pv = (const float4*)(projo + (size_t)(ab*T + tq)*H2 + dq*256);
  float p = 0.f;
  #pragma unroll 8
  for (int k4 = 0; k4 < 64; ++k4) {
    float4 a = hv[k4], q = pv[k4];
    p += a.x*q.x + a.y*q.y + a.z*q.z + a.w*q.w;
  }
  scp[tid] = p;
  __syncthreads();
  if (tid < 64) {
    float v = scp[tid*4] + scp[tid*4+1] + scp[tid*4+2] + scp[tid*4+3];
    float mx = v;
    #pragma unroll
    for (int d = 32; d; d >>= 1) mx = fmaxf(mx, __shfl_xor(mx, d, 64));
    float e = expf(v - mx);
    float sm = e;
    #pragma unroll
    for (int d = 32; d; d >>= 1) sm += __shfl_xor(sm, d, 64);
    scv[tid] = e * (1.f / sm) * (float)mask[ab*T + tid];
  }
  __syncthreads();
  {
    const int dl = tid & 127, th = tid >> 7;
    const int dg = aslice*128 + dl;
    float acc = 0.f;
    #pragma unroll 8
    for (int q = 0; q < 32; ++q) {
      int tt = th*32 + q;
      acc += scv[tt] * outbuf[(size_t)(ab*T + tt)*H2 + dg];
    }
    if (th == 1) p2[dl] = acc;
    __syncthreads();
    if (th == 0) st_wt(&ctxdst[dg*32 + ab], acc + p2[dl]);
  }
}

// ---------------- persistent encoder: rotating h buffers, INV-free barriers ----------
__global__ __launch_bounds__(256, 1) void encoder_persistent(
    const float* __restrict__ xg_f, const float* __restrict__ xg_b,
    const float* __restrict__ Whh_f, const float* __restrict__ Whh_b,
    const int* __restrict__ mask,
    float* __restrict__ hebufs,      // [2][64][512][32] rotating h
    const float* __restrict__ zeroh, // zeros (h(-1))
    float* __restrict__ outbuf,
    unsigned* __restrict__ eslots, unsigned* __restrict__ eflags)
{
  __shared__ float S_lds[9216];   // wave-private: wv*2304 + buf*1152, rows stride 36
  __shared__ float pacc[2048];
  __shared__ float g_lds[512];
  const int blk = blockIdx.x, tid = threadIdx.x;
  const int lane = tid & 63, wv = tid >> 6;
  const int dir = blk >> 7, nd = blk & 127;
  const int hibase = nd * 4;
  const int jj = tid & 7, kk = tid >> 3;
  const int kkl = lane >> 3;
  const float* xg  = dir ? xg_b : xg_f;
  const float* Whh = dir ? Whh_b : Whh_f;
  float* hebase = hebufs + (size_t)dir * 1048576;
  float* Sw = S_lds + wv*2304;

  float wge[2][16];
  #pragma unroll
  for (int p = 0; p < 2; ++p) {
    int jl = jj*2 + p;
    int j = (jl>>2)*512 + hibase + (jl&3);
    #pragma unroll
    for (int sc = 0; sc < 4; ++sc)
      #pragma unroll
      for (int i = 0; i < 4; ++i)
        wge[p][sc*4+i] = Whh[(size_t)j*512 + sc*128 + i*32 + kk];
  }
  float c_reg = 0.f;
  const int lr = lane >> 1, halfc = (lane & 1) * 16;
  const int grow = (lr >> 3)*32 + 8*wv + (lr & 7);

  for (int tt = 0; tt < 64; ++tt) {
    const int t = dir ? (63 - tt) : tt;
    const float* hc = tt ? (hebase + (size_t)(tt-1)*16384) : zeroh;
    float* hn = hebase + (size_t)tt*16384;

    float a0[32], a1[32];
    #pragma unroll
    for (int q = 0; q < 32; ++q) { a0[q] = 0.f; a1[q] = 0.f; }

    float4 r0, r1, r2, r3;
    {
      const float4* p = (const float4*)(hc + grow*32 + halfc);
      r0 = p[0]; r1 = p[1]; r2 = p[2]; r3 = p[3];
      float* d = Sw + lr*36 + halfc;
      *(float4*)d = r0; *(float4*)(d+4) = r1; *(float4*)(d+8) = r2; *(float4*)(d+12) = r3;
    }
    #pragma unroll
    for (int sc = 0; sc < 4; ++sc) {
      if (sc < 3) {
        const float4* p = (const float4*)(hc + ((sc+1)*128 + grow)*32 + halfc);
        r0 = p[0]; r1 = p[1]; r2 = p[2]; r3 = p[3];
      }
      const float* Sb = Sw + (sc & 1)*1152;
      #pragma unroll
      for (int i = 0; i < 4; ++i) {
        const float* sp = Sb + (i*8 + kkl)*36;
        float w0 = wge[0][sc*4+i], w1 = wge[1][sc*4+i];
        #pragma unroll
        for (int q = 0; q < 8; ++q) {
          float4 s4 = *(const float4*)(sp + q*4);
          a0[q*4+0] += w0*s4.x; a0[q*4+1] += w0*s4.y; a0[q*4+2] += w0*s4.z; a0[q*4+3] += w0*s4.w;
          a1[q*4+0] += w1*s4.x; a1[q*4+1] += w1*s4.y; a1[q*4+2] += w1*s4.z; a1[q*4+3] += w1*s4.w;
        }
      }
      if (sc < 3) {
        float* d = Sw + ((sc+1) & 1)*1152 + lr*36 + halfc;
        *(float4*)d = r0; *(float4*)(d+4) = r1; *(float4*)(d+8) = r2; *(float4*)(d+12) = r3;
      }
    }
    #pragma unroll
    for (int dd = 8; dd <= 32; dd <<= 1) {
      #pragma unroll
      for (int q = 0; q < 32; ++q) {
        a0[q] += __shfl_down(a0[q], dd, 64);
        a1[q] += __shfl_down(a1[q], dd, 64);
      }
    }
    if (lane < 8) {
      float* pw = &pacc[wv*512 + lane*64];
      #pragma unroll
      for (int q = 0; q < 32; ++q) { pw[q] = a0[q]; pw[32+q] = a1[q]; }
    }
    __syncthreads();
    #pragma unroll
    for (int r = 0; r < 2; ++r) {
      int o = tid + r*256;
      int jl = o >> 5, b = o & 31;
      int off = (jl>>1)*64 + (jl&1)*32 + b;
      float v = pacc[off] + pacc[512+off] + pacc[1024+off] + pacc[1536+off];
      v += xg[(size_t)(b*T + t)*2048 + (jl>>2)*512 + hibase + (jl&3)];
      g_lds[jl*32 + b] = v;
    }
    __syncthreads();
    if (tid < 128) {
      int hil = tid >> 5, b = tid & 31;
      float gi = g_lds[(0*4+hil)*32 + b];
      float gf = g_lds[(1*4+hil)*32 + b];
      float gg = g_lds[(2*4+hil)*32 + b];
      float go = g_lds[(3*4+hil)*32 + b];
      c_reg = sigm(gf)*c_reg + sigm(gi)*tanhf(gg);
      float h = sigm(go)*tanhf(c_reg);
      int hi = hibase + hil;
      st_wt(&hn[hi*32 + b], h);
      st_wt(&outbuf[(size_t)(b*T + t)*H2 + dir*512 + hi], h * (float)mask[b*T + t]);
    }
    pbar_na(eslots + (dir*64 + tt)*128, eflags + (dir*64 + tt)*256, nd, 128);
  }
}

// ---- decoder macros: wave-private staging (NO __syncthreads in K-loops) ----
#define GROW1(lr) (8*wv + ((lr) < 8 ? (lr) : 24 + (lr)))
#define GROW2(lr) (16*wv + (lr))
#define SLDG(qq, s) { int krr = (s)*64 + GROW1(lrow); \
  const float* bs = (krr < 1024) ? (hTc + krr*32) : (ctxc + (krr-1024)*32); \
  qq##a = *(const float4*)(bs + scol2); qq##b = *(const float4*)(bs + scol2 + 4); }
#define SLDS(qq, s) { int krr = (s)*64 + GROW2(lrow); \
  const float* bs = (krr < 1024) ? (hTn + krr*32) : (ctxc + (krr-1024)*32); \
  qq##a = *(const float4*)(bs + scol2); qq##b = *(const float4*)(bs + scol2 + 4); }
#define STW(qq, BUF) { float* d = Sw + (BUF)*576 + lrow*36 + scol2; \
  *(float4*)d = qq##a; *(float4*)(d+4) = qq##b; }
#define COMPG(sl, BUF) { const float* Sb = Sw + (BUF)*576; \
  _Pragma("unroll") for (int i = 0; i < 2; ++i) { \
    float w0 = Wg[jl0*2052 + (sl)*64 + i*32 + kkg]; \
    float w1 = Wg[jl1*2052 + (sl)*64 + i*32 + kkg]; \
    const float* sp = Sb + (i*8 + kkl)*36; \
    _Pragma("unroll") for (int q = 0; q < 8; ++q) { \
      float4 s4 = *(const float4*)(sp + q*4); \
      a0[q*4+0] += w0*s4.x; a0[q*4+1] += w0*s4.y; a0[q*4+2] += w0*s4.z; a0[q*4+3] += w0*s4.w; \
      a1[q*4+0] += w1*s4.x; a1[q*4+1] += w1*s4.y; a1[q*4+2] += w1*s4.z; a1[q*4+3] += w1*s4.w; } } }
#define COMPS(sl, BUF) { const float* sp = Sw + (BUF)*576 + lrow*36; \
  float w0 = ws0[sl], w1 = ws1[sl]; \
  _Pragma("unroll") for (int q = 0; q < 8; ++q) { \
    float4 s4 = *(const float4*)(sp + q*4); \
    a0[q*4+0] += w0*s4.x; a0[q*4+1] += w0*s4.y; a0[q*4+2] += w0*s4.z; a0[q*4+3] += w0*s4.w; \
    a1[q*4+0] += w1*s4.x; a1[q*4+1] += w1*s4.y; a1[q*4+2] += w1*s4.z; a1[q*4+3] += w1*s4.w; } }

// ---------------- persistent decoder: rotating state, INV-free barriers -----------------
// Dynamic LDS (floats): Wg 16x2052=32832 | S2 4x2x576=4608 | pacc 2048 | g_lds 512 = 160000 B
__global__ __launch_bounds__(256, 1) void decoder_persistent(
    const float* __restrict__ basep, const float* __restrict__ tagp,
    const float* __restrict__ dWhh,  const float* __restrict__ dWih,
    const float* __restrict__ Wout,  const float* __restrict__ bout,
    const float* __restrict__ projo, const float* __restrict__ outbuf,
    const int* __restrict__ mask,
    float* __restrict__ hbufs,       // [64][1024][32] rotating h (transposed)
    float* __restrict__ cbufs,       // [65][1024][32] rotating ctx (transposed)
    float* __restrict__ rbufs,       // [64][32][1024] rotating h (row-major)
    const float* __restrict__ zeroh, // [1024][32] zeros (h(-1))
    unsigned long long* __restrict__ argslot,
    unsigned* __restrict__ dslots, unsigned* __restrict__ dflags,
    float* __restrict__ out)
{
  extern __shared__ float dyn[];
  float* Wg    = dyn;           // 32832
  float* S2    = dyn + 32832;   // 4608 (wave-private: wv*1152 + buf*576)
  float* pacc  = dyn + 37440;   // 2048
  float* g_lds = dyn + 39488;   // 512

  const int blk = blockIdx.x, tid = threadIdx.x;
  const int lane = tid & 63, wv = tid >> 6;
  const int hibase = blk * 4;
  const int jj = lane & 7, kkl = lane >> 3;
  const int kkg = 8*wv + kkl;
  const int jl0 = jj*2, jl1 = jj*2 + 1;
  const int vv = tid & 3, kq = tid >> 2;
  const int vbase = blk * 8;
  const int lrow = lane >> 2, scol2 = (lane & 3) * 8;
  const int ab = blk & 31, aslice = blk >> 5;   // XCD-localized attend mapping
  float* Sw = S2 + wv*1152;

  // ---- preload gates weights into LDS (once) ----
  for (int jl = 0; jl < 16; ++jl) {
    int j = (jl>>2)*1024 + hibase + (jl&3);
    #pragma unroll
    for (int r = 0; r < 2; ++r) {
      int c = tid*4 + r*1024;
      float4 w;
      if (c < 1024) w = *(const float4*)(dWhh + (size_t)j*1024 + c);
      else          w = *(const float4*)(dWih + (size_t)j*2560 + 512 + (c - 1024));
      *(float4*)&Wg[jl*2052 + c] = w;
    }
  }
  // ---- scores weights in registers (64 floats/thread) ----
  float ws0[32], ws1[32];
  {
    int v0 = vbase + vv*2;
    #pragma unroll
    for (int s2 = 0; s2 < 32; ++s2) {
      ws0[s2] = Wout[(size_t)(v0+0)*2048 + s2*64 + kq];
      ws1[s2] = Wout[(size_t)(v0+1)*2048 + s2*64 + kq];
    }
  }

  float c_reg = 0.f;
  int bslot = 0;

  // ---- prologue: ctx(0) = attend(last_output) -> cbufs[0] ----
  {
    int len = -1;
    for (int i = 0; i < T; ++i) len += mask[ab*T + i];
    attend_slice(ab, aslice, outbuf + (size_t)(ab*T + len)*H2, cbufs,
                 outbuf, projo, mask, pacc, tid);
  }
  pbar_na(dslots + (bslot)*256, dflags + (bslot)*256, blk, 256); bslot++;

  for (int t = 0; t < T; ++t) {
    const float* hTc  = (t == 0) ? zeroh : (hbufs + (size_t)(t-1)*32768);
    float*       hTn  = hbufs + (size_t)t*32768;
    const float* ctxc = cbufs + (size_t)t*32768;
    float*       ctxn = cbufs + (size_t)(t+1)*32768;
    float*       hrw  = rbufs + (size_t)t*32768;

    const int b_own = tid & 31;
    const int jlA = tid >> 5, jlB = jlA + 8;
    const int jA = (jlA>>2)*1024 + hibase + (jlA&3);
    const int jB = (jlB>>2)*1024 + hibase + (jlB&3);
    float extA = basep[(size_t)(b_own*T + t)*G4 + jA];
    float extB = basep[(size_t)(b_own*T + t)*G4 + jB];
    if (t > 0) {
      unsigned long long sl64 = __hip_atomic_load(&argslot[((t+2)%3)*32 + b_own],
                                                  __ATOMIC_RELAXED, __HIP_MEMORY_SCOPE_AGENT);
      unsigned tg = ~(unsigned)sl64;
      extA += tagp[(size_t)tg*G4 + jA];
      extB += tagp[(size_t)tg*G4 + jB];
    }

    // ===== phase 1: gates (K=2048: h | ctx), wave-private staging, no K-loop syncs =====
    float a0[32], a1[32];
    #pragma unroll
    for (int q = 0; q < 32; ++q) { a0[q] = 0.f; a1[q] = 0.f; }
    {
      float4 q0a,q0b,q1a,q1b,q2a,q2b,q3a,q3b;
      SLDG(q0, 0) SLDG(q1, 1) SLDG(q2, 2) SLDG(q3, 3)
      STW(q0, 0)
      for (int g = 0; g < 8; ++g) {
        const int sl = g*4;
        if (sl+4 < 32) SLDG(q0, sl+4)
        COMPG(sl, 0)
        STW(q1, 1)
        if (sl+5 < 32) SLDG(q1, sl+5)
        COMPG(sl+1, 1)
        STW(q2, 0)
        if (sl+6 < 32) SLDG(q2, sl+6)
        COMPG(sl+2, 0)
        STW(q3, 1)
        if (sl+7 < 32) SLDG(q3, sl+7)
        COMPG(sl+3, 1)
        if (sl+4 < 32) STW(q0, 0)
      }
    }
    #pragma unroll
    for (int dd = 8; dd <= 32; dd <<= 1) {
      #pragma unroll
      for (int q = 0; q < 32; ++q) {
        a0[q] += __shfl_down(a0[q], dd, 64);
        a1[q] += __shfl_down(a1[q], dd, 64);
      }
    }
    if (lane < 8) {
      float* pw = &pacc[wv*512 + lane*64];
      #pragma unroll
      for (int q = 0; q < 32; ++q) { pw[q] = a0[q]; pw[32+q] = a1[q]; }
    }
    __syncthreads();
    #pragma unroll
    for (int r = 0; r < 2; ++r) {
      int o = tid + r*256;
      int jl = o >> 5, b = o & 31;
      int off = (jl>>1)*64 + (jl&1)*32 + b;
      float vsum = pacc[off] + pacc[512+off] + pacc[1024+off] + pacc[1536+off];
      vsum += (r == 0) ? extA : extB;
      g_lds[jl*32 + b] = vsum;
    }
    __syncthreads();
    if (tid < 128) {
      int hil = tid >> 5, b = tid & 31;
      float gi = g_lds[(0*4+hil)*32 + b];
      float gf = g_lds[(1*4+hil)*32 + b];
      float gg = g_lds[(2*4+hil)*32 + b];
      float go = g_lds[(3*4+hil)*32 + b];
      c_reg = sigm(gf)*c_reg + sigm(gi)*tanhf(gg);
      float h = sigm(go)*tanhf(c_reg);
      int hi = hibase + hil;
      st_wt(&hTn[hi*32 + b], h);
      st_wt(&hrw[b*1024 + hi], h);
    }
    pbar_na(dslots + (bslot)*256, dflags + (bslot)*256, blk, 256); bslot++;

    // ===== phase 2: scores (K=2048: h_new | ctx_old), wave-private staging =====
    #pragma unroll
    for (int q = 0; q < 32; ++q) { a0[q] = 0.f; a1[q] = 0.f; }
    {
      float4 q0a,q0b,q1a,q1b,q2a,q2b,q3a,q3b;
      SLDS(q0, 0) SLDS(q1, 1) SLDS(q2, 2) SLDS(q3, 3)
      STW(q0, 0)
      #pragma unroll
      for (int g = 0; g < 8; ++g) {
        const int sl = g*4;
        if (sl+4 < 32) SLDS(q0, sl+4)
        COMPS(sl, 0)
        STW(q1, 1)
        if (sl+5 < 32) SLDS(q1, sl+5)
        COMPS(sl+1, 1)
        STW(q2, 0)
        if (sl+6 < 32) SLDS(q2, sl+6)
        COMPS(sl+2, 0)
        STW(q3, 1)
        if (sl+7 < 32) SLDS(q3, sl+7)
        COMPS(sl+3, 1)
        if (sl+4 < 32) STW(q0, 0)
      }
    }
    #pragma unroll
    for (int dd = 4; dd <= 32; dd <<= 1) {
      #pragma unroll
      for (int q = 0; q < 32; ++q) {
        a0[q] += __shfl_down(a0[q], dd, 64);
        a1[q] += __shfl_down(a1[q], dd, 64);
      }
    }
    if (lane < 4) {
      float* pw = &pacc[wv*256 + lane*64];
      #pragma unroll
      for (int q = 0; q < 32; ++q) { pw[q] = a0[q]; pw[32+q] = a1[q]; }
    }
    __syncthreads();
    {
      int vl = tid & 7, b = tid >> 3;
      int off = (vl>>1)*64 + (vl&1)*32 + b;
      float s = pacc[off] + pacc[256+off] + pacc[512+off] + pacc[768+off];
      s += bout[vbase + vl];
      st_wt(&out[(size_t)(b*T + t)*V + vbase + vl], s);
      g_lds[vl*32 + b] = s;
    }
    __syncthreads();
    if (tid < 32) {
      int b = tid;
      float best = g_lds[b]; int bi = 0;
      #pragma unroll
      for (int vl = 1; vl < 8; ++vl) {
        float s = g_lds[vl*32 + b];
        if (s > best) { best = s; bi = vl; }
      }
      unsigned long long e = ((unsigned long long)fenc(best) << 32)
                           | (unsigned long long)(unsigned)(~(unsigned)(vbase + bi));
      atomicMax(&argslot[(t%3)*32 + b], e);
    } else if (blk == 0 && tid >= 32 && tid < 64) {
      __hip_atomic_store(&argslot[((t+1)%3)*32 + (tid - 32)], 0ull,
                         __ATOMIC_RELAXED, __HIP_MEMORY_SCOPE_AGENT);
    }
    if (t < 63) {
      __syncthreads();
      attend_slice(ab, aslice, hrw + ab*1024, ctxn, outbuf, projo, mask, pacc, tid);
    }
    pbar_na(dslots + (bslot)*256, dflags + (bslot)*256, blk, 256); bslot++;
  }
}

// ---------------- host launch ----------------
extern "C" void kernel_launch(void* const* d_in, const int* in_sizes, int n_in,
                              void* d_out, int out_size, void* d_ws, size_t ws_size,
                              hipStream_t stream)
{
  (void)in_sizes; (void)n_in; (void)out_size; (void)ws_size;
  const float* emb    = (const float*)d_in[0];
  const int*   mask   = (const int*)d_in[1];
  const float* Wih_f  = (const float*)d_in[2];
  const float* Whh_f  = (const float*)d_in[3];
  const float* bih_f  = (const float*)d_in[4];
  const float* bhh_f  = (const float*)d_in[5];
  const float* Wih_b  = (const float*)d_in[6];
  const float* Whh_b  = (const float*)d_in[7];
  const float* bih_b  = (const float*)d_in[8];
  const float* bhh_b  = (const float*)d_in[9];
  const float* attnW  = (const float*)d_in[10];
  const float* tagemb = (const float*)d_in[12];
  const float* dWih   = (const float*)d_in[13];
  const float* dWhh   = (const float*)d_in[14];
  const float* dbih   = (const float*)d_in[15];
  const float* dbhh   = (const float*)d_in[16];
  const float* Wout   = (const float*)d_in[17];
  const float* bout   = (const float*)d_in[18];
  float* out = (float*)d_out;

  float* ws = (float*)d_ws;
  // Region reuse across the pipeline (stream order guarantees no overlap in time):
  //  - xg region: GEMMs 1-2 write, encoder reads; then decoder recycles it as
  //    rotating state (hbufs/cbufs/rbufs).
  //  - basep region: encoder recycles it as rotating h (hebufs); then the basep
  //    GEMM overwrites it before the decoder reads basep.
  float* xg_f   = ws + 0;          // 4194304
  float* xg_b   = ws + 4194304;    // 4194304
  float* hbufs  = ws + 0;          // 64*32768 = 2097152   (decoder h rotation)
  float* cbufs  = ws + 2097152;    // 65*32768 = 2129920   (decoder ctx rotation)
  float* rbufs  = ws + 4227072;    // 64*32768 = 2097152   (decoder hrow rotation)
  float* outbuf = ws + 8388608;    // 2097152
  float* projo  = ws + 10485760;   // 2097152
  float* basep  = ws + 12582912;   // 8388608
  float* hebufs = ws + 12582912;   // 2*64*16384 = 2097152 (encoder h rotation, pre-basep)
  float* tagp   = ws + 20971520;   // 8388608
  // --- zeroed state block ---
  float* zeroh  = ws + 29360128;   // 32768 zeros (h(-1) for both kernels)
  unsigned long long* argslot = (unsigned long long*)(ws + 29589504);  // 96 u64 (192 fl)
  unsigned* dslots = (unsigned*)(ws + 29589696);   // 129*256 = 33024 u32
  unsigned* dflags = (unsigned*)(ws + 29622720);   // 129*256 = 33024 u32
  unsigned* eslots = (unsigned*)(ws + 29655744);   // 128*128 = 16384 u32
  unsigned* eflags = (unsigned*)(ws + 29672128);   // 128*256 = 32768 u32
  // end: 29704896 floats

  // allow 160000 B dynamic LDS for the decoder
  (void)hipFuncSetAttribute((const void*)decoder_persistent,
                            hipFuncAttributeMaxDynamicSharedMemorySize, 160000);

  // zero all persistent-kernel state every call (graph-replay deterministic)
  hipMemsetAsync((void*)(ws + 29360128), 0, (size_t)(29704896 - 29360128) * sizeof(float), stream);

  // xg = emb @ Wih^T + bih + bhh   (M=2048, N=2048, K=512)
  gemm_nt<<<dim3(16, 16), 256, 0, stream>>>(emb, 512, Wih_f, 512, xg_f, 2048, bih_f, bhh_f, 512);
  gemm_nt<<<dim3(16, 16), 256, 0, stream>>>(emb, 512, Wih_b, 512, xg_b, 2048, bih_b, bhh_b, 512);
  // tagp = tag_embed @ dec_Wih[:, :512]^T   (M=2048, N=4096, K=512)
  gemm_nt<<<dim3(32, 16), 256, 0, stream>>>(tagemb, 512, dWih, DEC_IN, tagp, G4, nullptr, nullptr, 512);
  // encoder scan (rotating h, INV-free barriers)
  encoder_persistent<<<256, 256, 0, stream>>>(xg_f, xg_b, Whh_f, Whh_b, mask,
                                              hebufs, zeroh, outbuf, eslots, eflags);
  // projo[bt,d] = sum_e attn_W[d,e]*output[bt,e]   (M=2048, N=1024, K=1024)
  gemm_nt<<<dim3(8, 16), 256, 0, stream>>>(outbuf, H2, attnW, H2, projo, H2, nullptr, nullptr, H2);
  // basep = aligned @ dec_Wih[:,1536:]^T + dbih + dbhh   (M=2048, N=4096, K=1024)
  gemm_nt<<<dim3(32, 16), 256, 0, stream>>>(outbuf, H2, dWih + 1536, DEC_IN, basep, G4, dbih, dbhh, H2);
  // persistent decoder (rotating state, INV-free barriers)
  decoder_persistent<<<256, 256, 160000, stream>>>(basep, tagp, dWhh, dWih, Wout, bout,
                                                   projo, outbuf, mask, hbufs, cbufs, rbufs, zeroh,
                                                   argslot, dslots, dflags, out);
}